// Round 5
// baseline (365.509 us; speedup 1.0000x reference)
//
#include <hip/hip_runtime.h>
#include <math.h>

#define HIDN 512
#define PROJ 1024
#define ATTN 128
#define BATCH 4
#define SEQ 2048
#define N1 (2*PROJ+ATTN)      // 2176
#define ROWS (BATCH*SEQ)      // 8192
#define QR 16                 // q-rows per flash block

typedef __attribute__((ext_vector_type(4))) float f32x4;
typedef __attribute__((ext_vector_type(8))) short bf16x8;

// bf16 <-> f32 via bit ops (round-to-nearest-even), no header dependency
__device__ __forceinline__ short f2bf(float x){
    unsigned u = __builtin_bit_cast(unsigned, x);
    unsigned rounding = 0x7fffu + ((u >> 16) & 1u);
    u += rounding;
    return (short)(u >> 16);
}
__device__ __forceinline__ float bf2f(short s){
    unsigned u = ((unsigned)(unsigned short)s) << 16;
    return __builtin_bit_cast(float, u);
}

__device__ __forceinline__ void gload16(const void* g, void* l){
    __builtin_amdgcn_global_load_lds((const __attribute__((address_space(1))) void*)g,
                                     (__attribute__((address_space(3))) void*)l,
                                     16, 0, 0);
}

// ---------------- m97-style bt-GEMM tile: C[128x128] = A[M][K] @ BT[N][K]^T
template<class Epi>
__device__ __forceinline__ void gemm_bt_tile(const short* __restrict__ A, int lda,
                                             const short* __restrict__ BT, int ldb,
                                             int m0, int n0, int K, Epi epi)
{
    __shared__ __align__(16) short lA[128*64];
    __shared__ __align__(16) short lB[128*64];
    const int t = threadIdx.x;
    const int lane = t & 63;
    const int w = t >> 6;
    const int wr = (w >> 1) * 64, wc = (w & 1) * 64;
    const int half = lane >> 4, l16 = lane & 15;

    f32x4 acc[4][4];
    #pragma unroll
    for (int i=0;i<4;i++)
        #pragma unroll
        for (int j=0;j<4;j++)
            acc[i][j] = (f32x4){0.f,0.f,0.f,0.f};

    for (int k0 = 0; k0 < K; k0 += 64) {
        #pragma unroll
        for (int i = 0; i < 4; i++) {
            int li = i*256 + t;
            int r = li >> 3, s = li & 7;
            gload16(A + (size_t)(m0+r)*lda + k0 + s*8, lA + li*8);
        }
        #pragma unroll
        for (int i = 0; i < 4; i++) {
            int li = i*256 + t;
            int r = li >> 3, s = li & 7;
            gload16(BT + (size_t)(n0+r)*ldb + k0 + s*8, lB + li*8);
        }
        __syncthreads();
        #pragma unroll
        for (int kk = 0; kk < 64; kk += 32) {
            bf16x8 af[4], bfr[4];
            #pragma unroll
            for (int i=0;i<4;i++)
                af[i] = *(const bf16x8*)(lA + (wr + i*16 + l16)*64 + kk + half*8);
            #pragma unroll
            for (int j=0;j<4;j++)
                bfr[j] = *(const bf16x8*)(lB + (wc + j*16 + l16)*64 + kk + half*8);
            #pragma unroll
            for (int i=0;i<4;i++)
                #pragma unroll
                for (int j=0;j<4;j++)
                    acc[i][j] = __builtin_amdgcn_mfma_f32_16x16x32_bf16(af[i], bfr[j], acc[i][j], 0, 0, 0);
        }
        __syncthreads();
    }
    #pragma unroll
    for (int i=0;i<4;i++)
        #pragma unroll
        for (int j=0;j<4;j++)
            #pragma unroll
            for (int q=0;q<4;q++)
                epi(m0 + wr + i*16 + half*4 + q, n0 + wc + j*16 + l16, acc[i][j][q]);
}

// ---------------- helpers ----------------
__global__ void k_cast_node(const float* __restrict__ in, short* __restrict__ out){
    int idx = blockIdx.x*256 + threadIdx.x;
    const float4 v = ((const float4*)in)[idx];
    short4 o; o.x = f2bf(v.x); o.y = f2bf(v.y); o.z = f2bf(v.z); o.w = f2bf(v.w);
    ((short4*)out)[idx] = o;
}

__global__ void k_transpose_cast(const float* __restrict__ in, short* __restrict__ out,
                                 int R, int C){
    __shared__ short tile[64][65];
    int r0 = blockIdx.y*64, c0 = blockIdx.x*64;
    int t = threadIdx.x;
    #pragma unroll
    for (int i=0;i<16;i++){
        int lin = i*256 + t; int r = lin>>6, c = lin&63;
        tile[r][c] = f2bf(in[(size_t)(r0+r)*C + c0+c]);
    }
    __syncthreads();
    #pragma unroll
    for (int i=0;i<16;i++){
        int lin = i*256 + t; int c = lin>>6, r = lin&63;
        out[(size_t)(c0+c)*R + r0+r] = tile[r][c];
    }
}

__global__ void k_transpose_v(const short* __restrict__ values, short* __restrict__ VT){
    __shared__ short tile[64][65];
    int z = blockIdx.z;
    int c0 = blockIdx.x*64, r0 = blockIdx.y*64;
    int t = threadIdx.x;
    #pragma unroll
    for (int i=0;i<16;i++){
        int lin = i*256 + t; int r = lin>>6, c = lin&63;
        tile[r][c] = values[(size_t)(z*SEQ + r0+r)*PROJ + c0+c];
    }
    __syncthreads();
    #pragma unroll
    for (int i=0;i<16;i++){
        int lin = i*256 + t; int c = lin>>6, r = lin&63;
        VT[((size_t)z*PROJ + c0+c)*SEQ + r0+r] = tile[r][c];
    }
}

// ---------------- GEMM1: silu(node@w1+b1) -> gates/values/base (bf16)
__global__ __launch_bounds__(256) void k_mm1(const short* __restrict__ nodeb,
        const short* __restrict__ w1T, const float* __restrict__ b1,
        short* __restrict__ gates, short* __restrict__ values, short* __restrict__ baseb){
    int n0 = blockIdx.x*128, m0 = blockIdx.y*128;
    gemm_bt_tile(nodeb, HIDN, w1T, HIDN, m0, n0, HIDN,
        [=](int row, int col, float v){
            v += b1[col];
            v = v / (1.f + __expf(-v));
            short bv = f2bf(v);
            if (col < PROJ)        gates [(size_t)row*PROJ + col]        = bv;
            else if (col < 2*PROJ) values[(size_t)row*PROJ + col-PROJ]   = bv;
            else                   baseb [(size_t)row*ATTN + col-2*PROJ] = bv;
        });
}

// ---------------- RoPE
__global__ void k_rope2(const short* __restrict__ baseb, const float* __restrict__ msw,
                        const float* __restrict__ msb, const float* __restrict__ scaling,
                        short* __restrict__ qb, short* __restrict__ kb){
    int idx = blockIdx.x*256 + threadIdx.x;
    int d = idx & 63;
    int row = idx >> 6;
    int l = row & (SEQ-1);
    float inv = exp2f(-(float)d * (13.287712379549449f/64.f));
    float ang = (float)l * inv;
    float s = sinf(ang), c = cosf(ang);
    const short* bp = baseb + (size_t)row*ATTN;
    float b_lo = bf2f(bp[d]), b_hi = bf2f(bp[d+64]);
    float x1q = b_lo*msw[d]        + msb[d];
    float x2q = b_hi*msw[d+64]     + msb[d+64];
    float x1k = b_lo*msw[128+d]    + msb[128+d];
    float x2k = b_hi*msw[128+d+64] + msb[128+d+64];
    float sc = scaling[0];
    qb[(size_t)row*ATTN + d]    = f2bf((x1q*c - x2q*s)*sc);
    qb[(size_t)row*ATTN + d+64] = f2bf((x2q*c + x1q*s)*sc);
    kb[(size_t)row*ATTN + d]    = f2bf(x1k*c - x2k*s);
    kb[(size_t)row*ATTN + d+64] = f2bf(x2k*c + x1k*s);
}

// ---------------- fully-fused flash attention:
// a2 = softmax(q@k^T + bias) @ V * gates, never materializing P in HBM.
// Block = 16 q-rows, 4 waves. S^T = K.Q^T layout: C cols(l16)=q, quad elems = 4
// consecutive kv -> float4 bias loads, cheap reductions. P bounced via LDS to
// A-frag layout; O[16q x 1024p] accumulated in registers (16 f32x4/lane/wave).
__global__ __launch_bounds__(256, 2) void k_flash(
        const short* __restrict__ qg, const short* __restrict__ kg,
        const float* __restrict__ bias, const short* __restrict__ VT,
        const short* __restrict__ gates, short* __restrict__ a2)
{
    __shared__ float s_m[4][16];
    __shared__ float s_l[4][16];
    __shared__ float s_mnow[2][16];
    __shared__ __align__(16) short ptile[2][QR][136];   // +8 pad: 2-way-max bank aliasing

    const int z = blockIdx.y;
    const int r0 = blockIdx.x * QR;
    const int t = threadIdx.x;
    const int w = t >> 6;
    const int lane = t & 63;
    const int l16 = lane & 15, half = lane >> 4;

    const short* Q  = qg + ((size_t)z*SEQ + r0)*ATTN;
    const short* K  = kg + (size_t)z*SEQ*ATTN;
    const float* Bb = bias + ((size_t)z*SEQ + r0)*SEQ;
    const short* Vz = VT + (size_t)z*PROJ*SEQ;

    // Q B-frags (rows q = l16), held all kernel
    bf16x8 qf[4];
    #pragma unroll
    for (int kc=0;kc<4;kc++)
        qf[kc] = *(const bf16x8*)(Q + (size_t)l16*ATTN + kc*32 + half*8);

    f32x4 O[16];
    #pragma unroll
    for (int nf=0;nf<16;nf++) O[nf] = (f32x4){0.f,0.f,0.f,0.f};

    float m_g = -3e38f, l_w = 0.f;                         // stats for q = l16
    float m_pv0=-3e38f, m_pv1=-3e38f, m_pv2=-3e38f, m_pv3=-3e38f;  // for q = half*4+e

    for (int j=0;j<16;j++){
        const int par = j & 1;
        // ---- S^T tile: rows kv = j*128 + w*32 + cf*16 + (half*4+e), cols q=l16
        f32x4 acc0 = (f32x4){0.f,0.f,0.f,0.f};
        f32x4 acc1 = (f32x4){0.f,0.f,0.f,0.f};
        {
            const short* Kc0 = K + (size_t)(j*128 + w*32 + l16)*ATTN;
            #pragma unroll
            for (int kc=0;kc<4;kc++){
                bf16x8 kf0 = *(const bf16x8*)(Kc0 + kc*32 + half*8);
                bf16x8 kf1 = *(const bf16x8*)(Kc0 + 16*ATTN + kc*32 + half*8);
                acc0 = __builtin_amdgcn_mfma_f32_16x16x32_bf16(kf0, qf[kc], acc0, 0,0,0);
                acc1 = __builtin_amdgcn_mfma_f32_16x16x32_bf16(kf1, qf[kc], acc1, 0,0,0);
            }
        }
        acc0 += *(const f32x4*)(Bb + (size_t)l16*SEQ + j*128 + w*32 + half*4);
        acc1 += *(const f32x4*)(Bb + (size_t)l16*SEQ + j*128 + w*32 + 16 + half*4);

        // ---- online max for q=l16 over this wave's 32 kv
        float tm = fmaxf(fmaxf(fmaxf(acc0[0],acc0[1]),fmaxf(acc0[2],acc0[3])),
                         fmaxf(fmaxf(acc1[0],acc1[1]),fmaxf(acc1[2],acc1[3])));
        tm = fmaxf(tm, __shfl_xor(tm,16,64));
        tm = fmaxf(tm, __shfl_xor(tm,32,64));
        if (half==0) s_m[w][l16] = tm;
        __syncthreads();                                   // barrier A
        float m_new = fmaxf(m_g, fmaxf(fmaxf(s_m[0][l16],s_m[1][l16]),
                                       fmaxf(s_m[2][l16],s_m[3][l16])));
        float p00 = __expf(acc0[0]-m_new), p01 = __expf(acc0[1]-m_new);
        float p02 = __expf(acc0[2]-m_new), p03 = __expf(acc0[3]-m_new);
        float p10 = __expf(acc1[0]-m_new), p11 = __expf(acc1[1]-m_new);
        float p12 = __expf(acc1[2]-m_new), p13 = __expf(acc1[3]-m_new);
        float ts = p00+p01+p02+p03+p10+p11+p12+p13;
        ts += __shfl_xor(ts,16,64);
        ts += __shfl_xor(ts,32,64);
        l_w = l_w * __expf(m_g - m_new) + ts;
        m_g = m_new;
        if (w==0 && half==0) s_mnow[par][l16] = m_new;
        // pack P (unnormalized exp) -> ptile[q][kv]
        {
            unsigned u0 = (unsigned)(unsigned short)f2bf(p00) | ((unsigned)(unsigned short)f2bf(p01)<<16);
            unsigned u1 = (unsigned)(unsigned short)f2bf(p02) | ((unsigned)(unsigned short)f2bf(p03)<<16);
            unsigned u2 = (unsigned)(unsigned short)f2bf(p10) | ((unsigned)(unsigned short)f2bf(p11)<<16);
            unsigned u3 = (unsigned)(unsigned short)f2bf(p12) | ((unsigned)(unsigned short)f2bf(p13)<<16);
            short* pd = &ptile[par][l16][w*32 + half*4];
            *(unsigned*)(pd)      = u0;
            *(unsigned*)(pd + 2)  = u1;
            *(unsigned*)(pd + 16) = u2;
            *(unsigned*)(pd + 18) = u3;
        }
        __syncthreads();                                   // barrier B
        // ---- rescale O by exp(m_old - m_new) per q-row (rows = half*4+e)
        {
            float mn0 = s_mnow[par][half*4+0];
            float mn1 = s_mnow[par][half*4+1];
            float mn2 = s_mnow[par][half*4+2];
            float mn3 = s_mnow[par][half*4+3];
            float f0 = __expf(m_pv0 - mn0); m_pv0 = mn0;
            float f1 = __expf(m_pv1 - mn1); m_pv1 = mn1;
            float f2 = __expf(m_pv2 - mn2); m_pv2 = mn2;
            float f3 = __expf(m_pv3 - mn3); m_pv3 = mn3;
            #pragma unroll
            for (int nf=0;nf<16;nf++){
                O[nf][0]*=f0; O[nf][1]*=f1; O[nf][2]*=f2; O[nf][3]*=f3;
            }
        }
        // ---- PV: O[16q x 256p] += P[16q x 128kv] . V[128kv x 256p]
        {
            bf16x8 pa0 = *(const bf16x8*)(&ptile[par][l16][ 0 + half*8]);
            bf16x8 pa1 = *(const bf16x8*)(&ptile[par][l16][32 + half*8]);
            bf16x8 pa2 = *(const bf16x8*)(&ptile[par][l16][64 + half*8]);
            bf16x8 pa3 = *(const bf16x8*)(&ptile[par][l16][96 + half*8]);
            #pragma unroll
            for (int nf=0;nf<16;nf++){
                const short* Vp = Vz + (size_t)(w*256 + nf*16 + l16)*SEQ + j*128;
                bf16x8 b0 = *(const bf16x8*)(Vp +  0 + half*8);
                bf16x8 b1 = *(const bf16x8*)(Vp + 32 + half*8);
                bf16x8 b2 = *(const bf16x8*)(Vp + 64 + half*8);
                bf16x8 b3 = *(const bf16x8*)(Vp + 96 + half*8);
                O[nf] = __builtin_amdgcn_mfma_f32_16x16x32_bf16(pa0, b0, O[nf], 0,0,0);
                O[nf] = __builtin_amdgcn_mfma_f32_16x16x32_bf16(pa1, b1, O[nf], 0,0,0);
                O[nf] = __builtin_amdgcn_mfma_f32_16x16x32_bf16(pa2, b2, O[nf], 0,0,0);
                O[nf] = __builtin_amdgcn_mfma_f32_16x16x32_bf16(pa3, b3, O[nf], 0,0,0);
            }
        }
    }
    // ---- final 1/l and epilogue: a2 = (O/l) * gates
    if (half==0) s_l[w][l16] = l_w;
    __syncthreads();
    float li0 = 1.f/(s_l[0][half*4+0]+s_l[1][half*4+0]+s_l[2][half*4+0]+s_l[3][half*4+0]);
    float li1 = 1.f/(s_l[0][half*4+1]+s_l[1][half*4+1]+s_l[2][half*4+1]+s_l[3][half*4+1]);
    float li2 = 1.f/(s_l[0][half*4+2]+s_l[1][half*4+2]+s_l[2][half*4+2]+s_l[3][half*4+2]);
    float li3 = 1.f/(s_l[0][half*4+3]+s_l[1][half*4+3]+s_l[2][half*4+3]+s_l[3][half*4+3]);
    #pragma unroll
    for (int nf=0;nf<16;nf++){
        int col = w*256 + nf*16 + l16;
        size_t base0 = ((size_t)z*SEQ + r0 + half*4)*PROJ + col;
        float v0 = O[nf][0]*li0 * bf2f(gates[base0]);
        float v1 = O[nf][1]*li1 * bf2f(gates[base0 + PROJ]);
        float v2 = O[nf][2]*li2 * bf2f(gates[base0 + 2*PROJ]);
        float v3 = O[nf][3]*li3 * bf2f(gates[base0 + 3*PROJ]);
        a2[base0]          = f2bf(v0);
        a2[base0 + PROJ]   = f2bf(v1);
        a2[base0 + 2*PROJ] = f2bf(v2);
        a2[base0 + 3*PROJ] = f2bf(v3);
    }
}

// ---------------- GEMM2: out = a2 @ w2 + b2  (f32 out)
__global__ __launch_bounds__(256) void k_mm2(const short* __restrict__ a2,
        const short* __restrict__ w2T, const float* __restrict__ b2,
        float* __restrict__ out){
    int n0 = blockIdx.x*128, m0 = blockIdx.y*128;
    gemm_bt_tile(a2, PROJ, w2T, PROJ, m0, n0, PROJ,
        [=](int r, int c, float v){
            out[(size_t)r*HIDN + c] = v + b2[c];
        });
}

extern "C" void kernel_launch(void* const* d_in, const int* in_sizes, int n_in,
                              void* d_out, int out_size, void* d_ws, size_t ws_size,
                              hipStream_t stream) {
    const float* node    = (const float*)d_in[0];
    const float* bias    = (const float*)d_in[1];
    const float* scaling = (const float*)d_in[2];
    const float* w1      = (const float*)d_in[3];
    const float* b1      = (const float*)d_in[4];
    const float* msw     = (const float*)d_in[5];
    const float* msb     = (const float*)d_in[6];
    const float* w2      = (const float*)d_in[7];
    const float* b2      = (const float*)d_in[8];
    float* out = (float*)d_out;

    char* p = (char*)d_ws;
    auto alloc = [&](size_t bytes){ char* r = p; p += (bytes + 255) & ~(size_t)255; return r; };
    short* nodeb  = (short*)alloc((size_t)ROWS*HIDN*2);
    short* w1T    = (short*)alloc((size_t)N1*HIDN*2);
    short* w2T    = (short*)alloc((size_t)HIDN*PROJ*2);
    short* gates  = (short*)alloc((size_t)ROWS*PROJ*2);
    short* values = (short*)alloc((size_t)ROWS*PROJ*2);
    short* VT     = (short*)alloc((size_t)BATCH*PROJ*SEQ*2);
    short* baseb  = (short*)alloc((size_t)ROWS*ATTN*2);
    short* qb     = (short*)alloc((size_t)ROWS*ATTN*2);
    short* kb     = (short*)alloc((size_t)ROWS*ATTN*2);
    short* a2buf  = (short*)alloc((size_t)ROWS*PROJ*2);

    k_cast_node<<<ROWS*HIDN/1024, 256, 0, stream>>>(node, nodeb);
    k_transpose_cast<<<dim3(N1/64, HIDN/64), 256, 0, stream>>>(w1, w1T, HIDN, N1);
    k_transpose_cast<<<dim3(HIDN/64, PROJ/64), 256, 0, stream>>>(w2, w2T, PROJ, HIDN);
    // 1) gva = silu(node@w1+b1)
    k_mm1<<<dim3(N1/128, ROWS/128), 256, 0, stream>>>(nodeb, w1T, b1, gates, values, baseb);
    // transpose values for PV B^T layout
    k_transpose_v<<<dim3(PROJ/64, SEQ/64, BATCH), 256, 0, stream>>>(values, VT);
    // 2) rope
    k_rope2<<<ROWS*64/256, 256, 0, stream>>>(baseb, msw, msb, scaling, qb, kb);
    // 3) fully-fused attention: a2 = softmax(qk^T+bias)@V * gates
    k_flash<<<dim3(SEQ/QR, BATCH), 256, 0, stream>>>(qb, kb, bias, VT, gates, a2buf);
    // 4) out = a2@w2 + b2
    k_mm2<<<dim3(HIDN/128, ROWS/128), 256, 0, stream>>>(a2buf, w2T, b2, out);
}

// Round 6
// 199.975 us; speedup vs baseline: 1.8278x; 1.8278x over previous
//
#include <hip/hip_runtime.h>
#include <math.h>

#define HIDN 512
#define PROJ 1024
#define ATTN 128
#define BATCH 4
#define SEQ 2048
#define N1 (2*PROJ+ATTN)      // 2176
#define ROWS (BATCH*SEQ)      // 8192
#define QR 16                 // q-rows per qksm block

typedef __attribute__((ext_vector_type(4))) float f32x4;
typedef __attribute__((ext_vector_type(8))) short bf16x8;

// bf16 <-> f32 via bit ops (round-to-nearest-even), no header dependency
__device__ __forceinline__ short f2bf(float x){
    unsigned u = __builtin_bit_cast(unsigned, x);
    unsigned rounding = 0x7fffu + ((u >> 16) & 1u);
    u += rounding;
    return (short)(u >> 16);
}
__device__ __forceinline__ float bf2f(short s){
    unsigned u = ((unsigned)(unsigned short)s) << 16;
    return __builtin_bit_cast(float, u);
}

__device__ __forceinline__ void gload16(const void* g, void* l){
    __builtin_amdgcn_global_load_lds((const __attribute__((address_space(1))) void*)g,
                                     (__attribute__((address_space(3))) void*)l,
                                     16, 0, 0);
}

// ---------------- m97-style bt-GEMM tile: C[128x128] = A[M][K] @ BT[N][K]^T
template<class Epi>
__device__ __forceinline__ void gemm_bt_tile(const short* __restrict__ A, int lda,
                                             const short* __restrict__ BT, int ldb,
                                             int m0, int n0, int K, Epi epi)
{
    __shared__ __align__(16) short lA[128*64];
    __shared__ __align__(16) short lB[128*64];
    const int t = threadIdx.x;
    const int lane = t & 63;
    const int w = t >> 6;
    const int wr = (w >> 1) * 64, wc = (w & 1) * 64;
    const int half = lane >> 4, l16 = lane & 15;

    f32x4 acc[4][4];
    #pragma unroll
    for (int i=0;i<4;i++)
        #pragma unroll
        for (int j=0;j<4;j++)
            acc[i][j] = (f32x4){0.f,0.f,0.f,0.f};

    for (int k0 = 0; k0 < K; k0 += 64) {
        #pragma unroll
        for (int i = 0; i < 4; i++) {
            int li = i*256 + t;
            int r = li >> 3, s = li & 7;
            gload16(A + (size_t)(m0+r)*lda + k0 + s*8, lA + li*8);
        }
        #pragma unroll
        for (int i = 0; i < 4; i++) {
            int li = i*256 + t;
            int r = li >> 3, s = li & 7;
            gload16(BT + (size_t)(n0+r)*ldb + k0 + s*8, lB + li*8);
        }
        __syncthreads();
        #pragma unroll
        for (int kk = 0; kk < 64; kk += 32) {
            bf16x8 af[4], bfr[4];
            #pragma unroll
            for (int i=0;i<4;i++)
                af[i] = *(const bf16x8*)(lA + (wr + i*16 + l16)*64 + kk + half*8);
            #pragma unroll
            for (int j=0;j<4;j++)
                bfr[j] = *(const bf16x8*)(lB + (wc + j*16 + l16)*64 + kk + half*8);
            #pragma unroll
            for (int i=0;i<4;i++)
                #pragma unroll
                for (int j=0;j<4;j++)
                    acc[i][j] = __builtin_amdgcn_mfma_f32_16x16x32_bf16(af[i], bfr[j], acc[i][j], 0, 0, 0);
        }
        __syncthreads();
    }
    #pragma unroll
    for (int i=0;i<4;i++)
        #pragma unroll
        for (int j=0;j<4;j++)
            #pragma unroll
            for (int q=0;q<4;q++)
                epi(m0 + wr + i*16 + half*4 + q, n0 + wc + j*16 + l16, acc[i][j][q]);
}

// ---------------- helpers ----------------
__global__ void k_cast_node(const float* __restrict__ in, short* __restrict__ out){
    int idx = blockIdx.x*256 + threadIdx.x;
    const float4 v = ((const float4*)in)[idx];
    short4 o; o.x = f2bf(v.x); o.y = f2bf(v.y); o.z = f2bf(v.z); o.w = f2bf(v.w);
    ((short4*)out)[idx] = o;
}

__global__ void k_transpose_cast(const float* __restrict__ in, short* __restrict__ out,
                                 int R, int C){
    __shared__ short tile[64][65];
    int r0 = blockIdx.y*64, c0 = blockIdx.x*64;
    int t = threadIdx.x;
    #pragma unroll
    for (int i=0;i<16;i++){
        int lin = i*256 + t; int r = lin>>6, c = lin&63;
        tile[r][c] = f2bf(in[(size_t)(r0+r)*C + c0+c]);
    }
    __syncthreads();
    #pragma unroll
    for (int i=0;i<16;i++){
        int lin = i*256 + t; int c = lin>>6, r = lin&63;
        out[(size_t)(c0+c)*R + r0+r] = tile[r][c];
    }
}

__global__ void k_transpose_v(const short* __restrict__ values, short* __restrict__ VT){
    __shared__ short tile[64][65];
    int z = blockIdx.z;
    int c0 = blockIdx.x*64, r0 = blockIdx.y*64;
    int t = threadIdx.x;
    #pragma unroll
    for (int i=0;i<16;i++){
        int lin = i*256 + t; int r = lin>>6, c = lin&63;
        tile[r][c] = values[(size_t)(z*SEQ + r0+r)*PROJ + c0+c];
    }
    __syncthreads();
    #pragma unroll
    for (int i=0;i<16;i++){
        int lin = i*256 + t; int c = lin>>6, r = lin&63;
        VT[((size_t)z*PROJ + c0+c)*SEQ + r0+r] = tile[r][c];
    }
}

// ---------------- GEMM1: silu(node@w1+b1) -> gates/values/base (bf16)
__global__ __launch_bounds__(256) void k_mm1(const short* __restrict__ nodeb,
        const short* __restrict__ w1T, const float* __restrict__ b1,
        short* __restrict__ gates, short* __restrict__ values, short* __restrict__ baseb){
    int n0 = blockIdx.x*128, m0 = blockIdx.y*128;
    gemm_bt_tile(nodeb, HIDN, w1T, HIDN, m0, n0, HIDN,
        [=](int row, int col, float v){
            v += b1[col];
            v = v / (1.f + __expf(-v));
            short bv = f2bf(v);
            if (col < PROJ)        gates [(size_t)row*PROJ + col]        = bv;
            else if (col < 2*PROJ) values[(size_t)row*PROJ + col-PROJ]   = bv;
            else                   baseb [(size_t)row*ATTN + col-2*PROJ] = bv;
        });
}

// ---------------- RoPE
__global__ void k_rope2(const short* __restrict__ baseb, const float* __restrict__ msw,
                        const float* __restrict__ msb, const float* __restrict__ scaling,
                        short* __restrict__ qb, short* __restrict__ kb){
    int idx = blockIdx.x*256 + threadIdx.x;
    int d = idx & 63;
    int row = idx >> 6;
    int l = row & (SEQ-1);
    float inv = exp2f(-(float)d * (13.287712379549449f/64.f));
    float ang = (float)l * inv;
    float s = sinf(ang), c = cosf(ang);
    const short* bp = baseb + (size_t)row*ATTN;
    float b_lo = bf2f(bp[d]), b_hi = bf2f(bp[d+64]);
    float x1q = b_lo*msw[d]        + msb[d];
    float x2q = b_hi*msw[d+64]     + msb[d+64];
    float x1k = b_lo*msw[128+d]    + msb[128+d];
    float x2k = b_hi*msw[128+d+64] + msb[128+d+64];
    float sc = scaling[0];
    qb[(size_t)row*ATTN + d]    = f2bf((x1q*c - x2q*s)*sc);
    qb[(size_t)row*ATTN + d+64] = f2bf((x2q*c + x1q*s)*sc);
    kb[(size_t)row*ATTN + d]    = f2bf(x1k*c - x2k*s);
    kb[(size_t)row*ATTN + d+64] = f2bf(x2k*c + x1k*s);
}

// ---------------- QK^T + bias + softmax -> compact bf16 P, ONE traversal.
// Block = 16 q-rows x full 2048 kv; S lives in registers (32 f32x4/lane).
// S^T = K.Q^T MFMA layout: col=l16=q, quad = 4 consecutive kv [R5-verified].
// Bias staged per-256-kv-chunk into LDS with coalesced f32x4 global reads.
// Wave w owns kv-16-tiles t where (t%4)==w within each chunk.
__global__ __launch_bounds__(256, 2) void k_qksm(
        const short* __restrict__ qg, const short* __restrict__ kg,
        const float* __restrict__ bias, short* __restrict__ P)
{
    __shared__ float bt[16][260];        // bias chunk, pad 4 (16.6 KB)
    __shared__ short pt[16][264];        // P chunk bounce (8.4 KB)
    __shared__ float s_m[4][16];
    __shared__ float s_l[4][16];

    const int z = blockIdx.y;
    const int r0 = blockIdx.x * QR;
    const int t = threadIdx.x;
    const int w = t >> 6;
    const int lane = t & 63;
    const int l16 = lane & 15, half = lane >> 4;

    const short* Q  = qg + ((size_t)z*SEQ + r0)*ATTN;
    const short* K  = kg + (size_t)z*SEQ*ATTN;
    const float* Bb = bias + ((size_t)z*SEQ + r0)*SEQ;
    short* Pp = P + ((size_t)z*SEQ + r0)*SEQ;

    // Q B-frags (rows q = l16)
    bf16x8 qf[4];
    #pragma unroll
    for (int kc=0;kc<4;kc++)
        qf[kc] = *(const bf16x8*)(Q + (size_t)l16*ATTN + kc*32 + half*8);

    f32x4 acc[32];
    #pragma unroll
    for (int qd=0; qd<32; qd++) acc[qd] = (f32x4){0.f,0.f,0.f,0.f};

    // ---- phase 1: S = K.Q^T + bias, accumulate in registers
    #pragma unroll
    for (int c=0; c<8; c++){
        // stage bias chunk [16 q][256 kv], coalesced f32x4
        #pragma unroll
        for (int i=0;i<4;i++){
            int idx = t + i*256;            // 0..1023 f32x4 units
            int row = idx >> 6, colq = idx & 63;
            *(f32x4*)&bt[row][colq*4] =
                *(const f32x4*)(Bb + (size_t)row*SEQ + c*256 + colq*4);
        }
        __syncthreads();
        #pragma unroll
        for (int i=0;i<4;i++){
            int qd = c*4 + i;
            int kvbase = c*256 + (i*4 + w)*16;
            const short* Kc = K + (size_t)(kvbase + l16)*ATTN;
            #pragma unroll
            for (int kc=0;kc<4;kc++){
                bf16x8 kf = *(const bf16x8*)(Kc + kc*32 + half*8);
                acc[qd] = __builtin_amdgcn_mfma_f32_16x16x32_bf16(kf, qf[kc], acc[qd], 0,0,0);
            }
            acc[qd] += *(const f32x4*)&bt[l16][(i*4 + w)*16 + half*4];
        }
        __syncthreads();   // before next chunk overwrites bt
    }

    // ---- phase 2: stats for q = l16 (this wave covers 512 kv)
    float tm = -3e38f;
    #pragma unroll
    for (int qd=0; qd<32; qd++)
        tm = fmaxf(tm, fmaxf(fmaxf(acc[qd][0],acc[qd][1]), fmaxf(acc[qd][2],acc[qd][3])));
    tm = fmaxf(tm, __shfl_xor(tm,16,64));
    tm = fmaxf(tm, __shfl_xor(tm,32,64));
    if (half==0) s_m[w][l16] = tm;
    __syncthreads();
    const float m = fmaxf(fmaxf(s_m[0][l16],s_m[1][l16]), fmaxf(s_m[2][l16],s_m[3][l16]));
    float ts = 0.f;
    #pragma unroll
    for (int qd=0; qd<32; qd++){
        acc[qd][0] = __expf(acc[qd][0]-m);
        acc[qd][1] = __expf(acc[qd][1]-m);
        acc[qd][2] = __expf(acc[qd][2]-m);
        acc[qd][3] = __expf(acc[qd][3]-m);
        ts += acc[qd][0]+acc[qd][1]+acc[qd][2]+acc[qd][3];
    }
    ts += __shfl_xor(ts,16,64);
    ts += __shfl_xor(ts,32,64);
    if (half==0) s_l[w][l16] = ts;
    __syncthreads();
    const float inv = 1.f/(s_l[0][l16]+s_l[1][l16]+s_l[2][l16]+s_l[3][l16]);

    // ---- phase 3: normalize, pack bf16, coalesced store via LDS bounce
    #pragma unroll
    for (int c=0; c<8; c++){
        #pragma unroll
        for (int i=0;i<4;i++){
            int qd = c*4 + i;
            int kvloc = (i*4 + w)*16 + half*4;
            f32x4 p4 = acc[qd] * inv;
            unsigned u0 = (unsigned)(unsigned short)f2bf(p4[0]) | ((unsigned)(unsigned short)f2bf(p4[1])<<16);
            unsigned u1 = (unsigned)(unsigned short)f2bf(p4[2]) | ((unsigned)(unsigned short)f2bf(p4[3])<<16);
            *(unsigned*)&pt[l16][kvloc]     = u0;
            *(unsigned*)&pt[l16][kvloc + 2] = u1;
        }
        __syncthreads();
        #pragma unroll
        for (int i=0;i<2;i++){
            int idx = t + i*256;            // 0..511 groups of 8 bf16
            int row = idx >> 5, colg = idx & 31;
            *(bf16x8*)(Pp + (size_t)row*SEQ + c*256 + colg*8) =
                *(const bf16x8*)&pt[row][colg*8];
        }
        __syncthreads();   // before next chunk overwrites pt
    }
}

// ---------------- PV: a2 = (P @ V) * gates  (bf16 out)
__global__ __launch_bounds__(256) void k_pv2(const short* __restrict__ P,
        const short* __restrict__ VT, const short* __restrict__ gates,
        short* __restrict__ a2){
    int z = blockIdx.z;
    const short* A = P  + (size_t)z*SEQ*SEQ;       // compact bf16, lda = SEQ
    const short* B = VT + (size_t)z*PROJ*SEQ;      // ldb = SEQ
    int n0 = blockIdx.x*128, m0 = blockIdx.y*128;
    gemm_bt_tile(A, SEQ, B, SEQ, m0, n0, SEQ,
        [=](int r, int c, float v){
            size_t gi = ((size_t)z*SEQ + r)*PROJ + c;
            a2[gi] = f2bf(v * bf2f(gates[gi]));
        });
}

// ---------------- GEMM2: out = a2 @ w2 + b2  (f32 out)
__global__ __launch_bounds__(256) void k_mm2(const short* __restrict__ a2,
        const short* __restrict__ w2T, const float* __restrict__ b2,
        float* __restrict__ out){
    int n0 = blockIdx.x*128, m0 = blockIdx.y*128;
    gemm_bt_tile(a2, PROJ, w2T, PROJ, m0, n0, PROJ,
        [=](int r, int c, float v){
            out[(size_t)r*HIDN + c] = v + b2[c];
        });
}

extern "C" void kernel_launch(void* const* d_in, const int* in_sizes, int n_in,
                              void* d_out, int out_size, void* d_ws, size_t ws_size,
                              hipStream_t stream) {
    const float* node    = (const float*)d_in[0];
    const float* bias    = (const float*)d_in[1];
    const float* scaling = (const float*)d_in[2];
    const float* w1      = (const float*)d_in[3];
    const float* b1      = (const float*)d_in[4];
    const float* msw     = (const float*)d_in[5];
    const float* msb     = (const float*)d_in[6];
    const float* w2      = (const float*)d_in[7];
    const float* b2      = (const float*)d_in[8];
    float* out = (float*)d_out;

    char* p = (char*)d_ws;
    auto alloc = [&](size_t bytes){ char* r = p; p += (bytes + 255) & ~(size_t)255; return r; };
    short* nodeb  = (short*)alloc((size_t)ROWS*HIDN*2);
    short* w1T    = (short*)alloc((size_t)N1*HIDN*2);
    short* w2T    = (short*)alloc((size_t)HIDN*PROJ*2);
    short* gates  = (short*)alloc((size_t)ROWS*PROJ*2);
    short* values = (short*)alloc((size_t)ROWS*PROJ*2);
    short* VT     = (short*)alloc((size_t)BATCH*PROJ*SEQ*2);
    short* baseb  = (short*)alloc((size_t)ROWS*ATTN*2);
    short* qb     = (short*)alloc((size_t)ROWS*ATTN*2);
    short* kb     = (short*)alloc((size_t)ROWS*ATTN*2);
    short* Pbuf   = (short*)alloc((size_t)BATCH*SEQ*SEQ*2);
    short* a2buf  = (short*)alloc((size_t)ROWS*PROJ*2);

    k_cast_node<<<ROWS*HIDN/1024, 256, 0, stream>>>(node, nodeb);
    k_transpose_cast<<<dim3(N1/64, HIDN/64), 256, 0, stream>>>(w1, w1T, HIDN, N1);
    k_transpose_cast<<<dim3(HIDN/64, PROJ/64), 256, 0, stream>>>(w2, w2T, PROJ, HIDN);
    // 1) gva = silu(node@w1+b1)
    k_mm1<<<dim3(N1/128, ROWS/128), 256, 0, stream>>>(nodeb, w1T, b1, gates, values, baseb);
    // transpose values for PV B^T layout
    k_transpose_v<<<dim3(PROJ/64, SEQ/64, BATCH), 256, 0, stream>>>(values, VT);
    // 2) rope
    k_rope2<<<ROWS*64/256, 256, 0, stream>>>(baseb, msw, msb, scaling, qb, kb);
    // 3) one-traversal qk^T + bias + softmax -> P (bf16, register-resident S)
    k_qksm<<<dim3(SEQ/QR, BATCH), 256, 0, stream>>>(qb, kb, bias, Pbuf);
    // 3c) a2 = (P@V)*gates
    k_pv2<<<dim3(PROJ/128, SEQ/128, BATCH), 256, 0, stream>>>(Pbuf, VT, gates, a2buf);
    // 4) out = a2@w2 + b2
    k_mm2<<<dim3(HIDN/128, ROWS/128), 256, 0, stream>>>(a2buf, w2T, b2, out);
}

// Round 7
// 186.484 us; speedup vs baseline: 1.9600x; 1.0723x over previous
//
#include <hip/hip_runtime.h>
#include <math.h>

#define HIDN 512
#define PROJ 1024
#define ATTN 128
#define BATCH 4
#define SEQ 2048
#define N1 (2*PROJ+ATTN)      // 2176
#define ROWS (BATCH*SEQ)      // 8192
#define QR 16                 // q-rows per qksm block

typedef __attribute__((ext_vector_type(4))) float f32x4;
typedef __attribute__((ext_vector_type(8))) short bf16x8;

// bf16 <-> f32 via bit ops (round-to-nearest-even), no header dependency
__device__ __forceinline__ short f2bf(float x){
    unsigned u = __builtin_bit_cast(unsigned, x);
    unsigned rounding = 0x7fffu + ((u >> 16) & 1u);
    u += rounding;
    return (short)(u >> 16);
}
__device__ __forceinline__ float bf2f(short s){
    unsigned u = ((unsigned)(unsigned short)s) << 16;
    return __builtin_bit_cast(float, u);
}

__device__ __forceinline__ void gload16(const void* g, void* l){
    __builtin_amdgcn_global_load_lds((const __attribute__((address_space(1))) void*)g,
                                     (__attribute__((address_space(3))) void*)l,
                                     16, 0, 0);
}

// ---------------- m97-style bt-GEMM tile: C[128x128] = A[M][K] @ BT[N][K]^T
template<class Epi>
__device__ __forceinline__ void gemm_bt_tile(const short* __restrict__ A, int lda,
                                             const short* __restrict__ BT, int ldb,
                                             int m0, int n0, int K, Epi epi)
{
    __shared__ __align__(16) short lA[128*64];
    __shared__ __align__(16) short lB[128*64];
    const int t = threadIdx.x;
    const int lane = t & 63;
    const int w = t >> 6;
    const int wr = (w >> 1) * 64, wc = (w & 1) * 64;
    const int half = lane >> 4, l16 = lane & 15;

    f32x4 acc[4][4];
    #pragma unroll
    for (int i=0;i<4;i++)
        #pragma unroll
        for (int j=0;j<4;j++)
            acc[i][j] = (f32x4){0.f,0.f,0.f,0.f};

    for (int k0 = 0; k0 < K; k0 += 64) {
        #pragma unroll
        for (int i = 0; i < 4; i++) {
            int li = i*256 + t;
            int r = li >> 3, s = li & 7;
            gload16(A + (size_t)(m0+r)*lda + k0 + s*8, lA + li*8);
        }
        #pragma unroll
        for (int i = 0; i < 4; i++) {
            int li = i*256 + t;
            int r = li >> 3, s = li & 7;
            gload16(BT + (size_t)(n0+r)*ldb + k0 + s*8, lB + li*8);
        }
        __syncthreads();
        #pragma unroll
        for (int kk = 0; kk < 64; kk += 32) {
            bf16x8 af[4], bfr[4];
            #pragma unroll
            for (int i=0;i<4;i++)
                af[i] = *(const bf16x8*)(lA + (wr + i*16 + l16)*64 + kk + half*8);
            #pragma unroll
            for (int j=0;j<4;j++)
                bfr[j] = *(const bf16x8*)(lB + (wc + j*16 + l16)*64 + kk + half*8);
            #pragma unroll
            for (int i=0;i<4;i++)
                #pragma unroll
                for (int j=0;j<4;j++)
                    acc[i][j] = __builtin_amdgcn_mfma_f32_16x16x32_bf16(af[i], bfr[j], acc[i][j], 0, 0, 0);
        }
        __syncthreads();
    }
    #pragma unroll
    for (int i=0;i<4;i++)
        #pragma unroll
        for (int j=0;j<4;j++)
            #pragma unroll
            for (int q=0;q<4;q++)
                epi(m0 + wr + i*16 + half*4 + q, n0 + wc + j*16 + l16, acc[i][j][q]);
}

// ---------------- helpers ----------------
__global__ void k_cast_node(const float* __restrict__ in, short* __restrict__ out){
    int idx = blockIdx.x*256 + threadIdx.x;
    const float4 v = ((const float4*)in)[idx];
    short4 o; o.x = f2bf(v.x); o.y = f2bf(v.y); o.z = f2bf(v.z); o.w = f2bf(v.w);
    ((short4*)out)[idx] = o;
}

__global__ void k_transpose_cast(const float* __restrict__ in, short* __restrict__ out,
                                 int R, int C){
    __shared__ short tile[64][65];
    int r0 = blockIdx.y*64, c0 = blockIdx.x*64;
    int t = threadIdx.x;
    #pragma unroll
    for (int i=0;i<16;i++){
        int lin = i*256 + t; int r = lin>>6, c = lin&63;
        tile[r][c] = f2bf(in[(size_t)(r0+r)*C + c0+c]);
    }
    __syncthreads();
    #pragma unroll
    for (int i=0;i<16;i++){
        int lin = i*256 + t; int c = lin>>6, r = lin&63;
        out[(size_t)(c0+c)*R + r0+r] = tile[r][c];
    }
}

__global__ void k_transpose_v(const short* __restrict__ values, short* __restrict__ VT){
    __shared__ short tile[64][65];
    int z = blockIdx.z;
    int c0 = blockIdx.x*64, r0 = blockIdx.y*64;
    int t = threadIdx.x;
    #pragma unroll
    for (int i=0;i<16;i++){
        int lin = i*256 + t; int r = lin>>6, c = lin&63;
        tile[r][c] = values[(size_t)(z*SEQ + r0+r)*PROJ + c0+c];
    }
    __syncthreads();
    #pragma unroll
    for (int i=0;i<16;i++){
        int lin = i*256 + t; int c = lin>>6, r = lin&63;
        VT[((size_t)z*PROJ + c0+c)*SEQ + r0+r] = tile[r][c];
    }
}

// ---------------- GEMM1: silu(node@w1+b1) -> gates/values/base (bf16)
// 1D grid, XCD-chunked swizzle (1088 blocks = 8*136)
__global__ __launch_bounds__(256) void k_mm1(const short* __restrict__ nodeb,
        const short* __restrict__ w1T, const float* __restrict__ b1,
        short* __restrict__ gates, short* __restrict__ values, short* __restrict__ baseb){
    int b = blockIdx.x;
    int wg = (b & 7) * (N1/128*64/8) + (b >> 3);   // cpx = 136
    int n0 = (wg % (N1/128))*128, m0 = (wg / (N1/128))*128;
    gemm_bt_tile(nodeb, HIDN, w1T, HIDN, m0, n0, HIDN,
        [=](int row, int col, float v){
            v += b1[col];
            v = v / (1.f + __expf(-v));
            short bv = f2bf(v);
            if (col < PROJ)        gates [(size_t)row*PROJ + col]        = bv;
            else if (col < 2*PROJ) values[(size_t)row*PROJ + col-PROJ]   = bv;
            else                   baseb [(size_t)row*ATTN + col-2*PROJ] = bv;
        });
}

// ---------------- RoPE
__global__ void k_rope2(const short* __restrict__ baseb, const float* __restrict__ msw,
                        const float* __restrict__ msb, const float* __restrict__ scaling,
                        short* __restrict__ qb, short* __restrict__ kb){
    int idx = blockIdx.x*256 + threadIdx.x;
    int d = idx & 63;
    int row = idx >> 6;
    int l = row & (SEQ-1);
    float inv = exp2f(-(float)d * (13.287712379549449f/64.f));
    float ang = (float)l * inv;
    float s = sinf(ang), c = cosf(ang);
    const short* bp = baseb + (size_t)row*ATTN;
    float b_lo = bf2f(bp[d]), b_hi = bf2f(bp[d+64]);
    float x1q = b_lo*msw[d]        + msb[d];
    float x2q = b_hi*msw[d+64]     + msb[d+64];
    float x1k = b_lo*msw[128+d]    + msb[128+d];
    float x2k = b_hi*msw[128+d+64] + msb[128+d+64];
    float sc = scaling[0];
    qb[(size_t)row*ATTN + d]    = f2bf((x1q*c - x2q*s)*sc);
    qb[(size_t)row*ATTN + d+64] = f2bf((x2q*c + x1q*s)*sc);
    kb[(size_t)row*ATTN + d]    = f2bf(x1k*c - x2k*s);
    kb[(size_t)row*ATTN + d+64] = f2bf(x2k*c + x1k*s);
}

// ---------------- QK^T + bias + softmax -> compact bf16 P, ONE traversal.
// v2: 512 threads / 8 waves; wave w owns 256 kv; S = 16 f32x4/lane (64 VGPR).
// Bias chunks (16x256 f32) double-hidden: register prefetch of chunk c+1
// issued before chunk c's MFMA phase. S^T = K.Q^T layout [R5/R6-verified].
__global__ __launch_bounds__(512, 4) void k_qksm(
        const short* __restrict__ qg, const short* __restrict__ kg,
        const float* __restrict__ bias, short* __restrict__ P)
{
    __shared__ float bt[16][260];        // bias chunk, pad 4
    __shared__ short pt[16][264];        // P chunk bounce
    __shared__ float s_m[8][16];
    __shared__ float s_l[8][16];

    const int z = blockIdx.y;
    const int r0 = blockIdx.x * QR;
    const int t = threadIdx.x;
    const int w = t >> 6;                // 0..7
    const int lane = t & 63;
    const int l16 = lane & 15, half = lane >> 4;

    const short* Q  = qg + ((size_t)z*SEQ + r0)*ATTN;
    const short* K  = kg + (size_t)z*SEQ*ATTN;
    const float* Bb = bias + ((size_t)z*SEQ + r0)*SEQ;
    short* Pp = P + ((size_t)z*SEQ + r0)*SEQ;

    // Q B-frags (rows q = l16)
    bf16x8 qf[4];
    #pragma unroll
    for (int kc=0;kc<4;kc++)
        qf[kc] = *(const bf16x8*)(Q + (size_t)l16*ATTN + kc*32 + half*8);

    f32x4 acc[16];
    #pragma unroll
    for (int qd=0; qd<16; qd++) acc[qd] = (f32x4){0.f,0.f,0.f,0.f};

    // bias prefetch: thread t stages units t (rows 0-7) and t+512 (rows 8-15)
    const int brow = t >> 6, bcol = (t & 63)*4;
    f32x4 pr0 = *(const f32x4*)(Bb + (size_t)brow*SEQ + bcol);
    f32x4 pr1 = *(const f32x4*)(Bb + (size_t)(8+brow)*SEQ + bcol);

    // ---- phase 1: S = K.Q^T + bias, accumulate in registers
    #pragma unroll
    for (int c=0; c<8; c++){
        __syncthreads();                  // prev chunk's bt reads complete
        *(f32x4*)&bt[brow][bcol]   = pr0;
        *(f32x4*)&bt[8+brow][bcol] = pr1;
        __syncthreads();                  // bt ready
        if (c < 7){
            pr0 = *(const f32x4*)(Bb + (size_t)brow*SEQ + (c+1)*256 + bcol);
            pr1 = *(const f32x4*)(Bb + (size_t)(8+brow)*SEQ + (c+1)*256 + bcol);
        }
        #pragma unroll
        for (int i=0;i<2;i++){
            int qd = c*2 + i;
            int tile = w*2 + i;           // 16-kv tile within chunk
            const short* Kc = K + (size_t)(c*256 + tile*16 + l16)*ATTN;
            #pragma unroll
            for (int kc=0;kc<4;kc++){
                bf16x8 kf = *(const bf16x8*)(Kc + kc*32 + half*8);
                acc[qd] = __builtin_amdgcn_mfma_f32_16x16x32_bf16(kf, qf[kc], acc[qd], 0,0,0);
            }
            acc[qd] += *(const f32x4*)&bt[l16][tile*16 + half*4];
        }
    }

    // ---- phase 2: stats for q = l16 (wave covers 256 kv; 8 waves total)
    float tm = -3e38f;
    #pragma unroll
    for (int qd=0; qd<16; qd++)
        tm = fmaxf(tm, fmaxf(fmaxf(acc[qd][0],acc[qd][1]), fmaxf(acc[qd][2],acc[qd][3])));
    tm = fmaxf(tm, __shfl_xor(tm,16,64));
    tm = fmaxf(tm, __shfl_xor(tm,32,64));
    if (half==0) s_m[w][l16] = tm;
    __syncthreads();
    float m = -3e38f;
    #pragma unroll
    for (int ww=0; ww<8; ww++) m = fmaxf(m, s_m[ww][l16]);
    float ts = 0.f;
    #pragma unroll
    for (int qd=0; qd<16; qd++){
        acc[qd][0] = __expf(acc[qd][0]-m);
        acc[qd][1] = __expf(acc[qd][1]-m);
        acc[qd][2] = __expf(acc[qd][2]-m);
        acc[qd][3] = __expf(acc[qd][3]-m);
        ts += acc[qd][0]+acc[qd][1]+acc[qd][2]+acc[qd][3];
    }
    ts += __shfl_xor(ts,16,64);
    ts += __shfl_xor(ts,32,64);
    if (half==0) s_l[w][l16] = ts;
    __syncthreads();
    float sum = 0.f;
    #pragma unroll
    for (int ww=0; ww<8; ww++) sum += s_l[ww][l16];
    const float inv = 1.f/sum;

    // ---- phase 3: normalize, pack bf16, coalesced store via LDS bounce
    #pragma unroll
    for (int c=0; c<8; c++){
        #pragma unroll
        for (int i=0;i<2;i++){
            int qd = c*2 + i;
            int kvloc = (w*2 + i)*16 + half*4;
            f32x4 p4 = acc[qd] * inv;
            unsigned u0 = (unsigned)(unsigned short)f2bf(p4[0]) | ((unsigned)(unsigned short)f2bf(p4[1])<<16);
            unsigned u1 = (unsigned)(unsigned short)f2bf(p4[2]) | ((unsigned)(unsigned short)f2bf(p4[3])<<16);
            *(unsigned*)&pt[l16][kvloc]     = u0;
            *(unsigned*)&pt[l16][kvloc + 2] = u1;
        }
        __syncthreads();
        {
            int row = t >> 5, colg = t & 31;   // 512 threads = 16 rows x 32 groups
            *(bf16x8*)(Pp + (size_t)row*SEQ + c*256 + colg*8) =
                *(const bf16x8*)&pt[row][colg*8];
        }
        __syncthreads();
    }
}

// ---------------- PV: a2 = (P @ V) * gates  (bf16 out)
// 1D grid, XCD-chunked swizzle (512 blocks = 8*64)
__global__ __launch_bounds__(256) void k_pv2(const short* __restrict__ P,
        const short* __restrict__ VT, const short* __restrict__ gates,
        short* __restrict__ a2){
    int b = blockIdx.x;
    int wg = (b & 7) * 64 + (b >> 3);
    int xx = wg & 7, yy = (wg >> 3) & 15, z = wg >> 7;
    const short* A = P  + (size_t)z*SEQ*SEQ;
    const short* B = VT + (size_t)z*PROJ*SEQ;
    int n0 = xx*128, m0 = yy*128;
    gemm_bt_tile(A, SEQ, B, SEQ, m0, n0, SEQ,
        [=](int r, int c, float v){
            size_t gi = ((size_t)z*SEQ + r)*PROJ + c;
            a2[gi] = f2bf(v * bf2f(gates[gi]));
        });
}

// ---------------- GEMM2: out = a2 @ w2 + b2  (f32 out)
// 1D grid, XCD-chunked swizzle (256 blocks = 8*32)
__global__ __launch_bounds__(256) void k_mm2(const short* __restrict__ a2,
        const short* __restrict__ w2T, const float* __restrict__ b2,
        float* __restrict__ out){
    int b = blockIdx.x;
    int wg = (b & 7) * 32 + (b >> 3);
    int n0 = (wg & 3)*128, m0 = (wg >> 2)*128;
    gemm_bt_tile(a2, PROJ, w2T, PROJ, m0, n0, PROJ,
        [=](int r, int c, float v){
            out[(size_t)r*HIDN + c] = v + b2[c];
        });
}

extern "C" void kernel_launch(void* const* d_in, const int* in_sizes, int n_in,
                              void* d_out, int out_size, void* d_ws, size_t ws_size,
                              hipStream_t stream) {
    const float* node    = (const float*)d_in[0];
    const float* bias    = (const float*)d_in[1];
    const float* scaling = (const float*)d_in[2];
    const float* w1      = (const float*)d_in[3];
    const float* b1      = (const float*)d_in[4];
    const float* msw     = (const float*)d_in[5];
    const float* msb     = (const float*)d_in[6];
    const float* w2      = (const float*)d_in[7];
    const float* b2      = (const float*)d_in[8];
    float* out = (float*)d_out;

    char* p = (char*)d_ws;
    auto alloc = [&](size_t bytes){ char* r = p; p += (bytes + 255) & ~(size_t)255; return r; };
    short* nodeb  = (short*)alloc((size_t)ROWS*HIDN*2);
    short* w1T    = (short*)alloc((size_t)N1*HIDN*2);
    short* w2T    = (short*)alloc((size_t)HIDN*PROJ*2);
    short* gates  = (short*)alloc((size_t)ROWS*PROJ*2);
    short* values = (short*)alloc((size_t)ROWS*PROJ*2);
    short* VT     = (short*)alloc((size_t)BATCH*PROJ*SEQ*2);
    short* baseb  = (short*)alloc((size_t)ROWS*ATTN*2);
    short* qb     = (short*)alloc((size_t)ROWS*ATTN*2);
    short* kb     = (short*)alloc((size_t)ROWS*ATTN*2);
    short* Pbuf   = (short*)alloc((size_t)BATCH*SEQ*SEQ*2);
    short* a2buf  = (short*)alloc((size_t)ROWS*PROJ*2);

    k_cast_node<<<ROWS*HIDN/1024, 256, 0, stream>>>(node, nodeb);
    k_transpose_cast<<<dim3(N1/64, HIDN/64), 256, 0, stream>>>(w1, w1T, HIDN, N1);
    k_transpose_cast<<<dim3(HIDN/64, PROJ/64), 256, 0, stream>>>(w2, w2T, PROJ, HIDN);
    // 1) gva = silu(node@w1+b1)
    k_mm1<<<(N1/128)*(ROWS/128), 256, 0, stream>>>(nodeb, w1T, b1, gates, values, baseb);
    // transpose values for PV B^T layout
    k_transpose_v<<<dim3(PROJ/64, SEQ/64, BATCH), 256, 0, stream>>>(values, VT);
    // 2) rope
    k_rope2<<<ROWS*64/256, 256, 0, stream>>>(baseb, msw, msb, scaling, qb, kb);
    // 3) one-traversal qk^T + bias + softmax -> P (bf16), 8 waves/block
    k_qksm<<<dim3(SEQ/QR, BATCH), 512, 0, stream>>>(qb, kb, bias, Pbuf);
    // 3c) a2 = (P@V)*gates
    k_pv2<<<(PROJ/128)*(SEQ/128)*BATCH, 256, 0, stream>>>(Pbuf, VT, gates, a2buf);
    // 4) out = a2@w2 + b2
    k_mm2<<<(HIDN/128)*(ROWS/128), 256, 0, stream>>>(a2buf, w2T, b2, out);
}

// Round 8
// 172.859 us; speedup vs baseline: 2.1145x; 1.0788x over previous
//
#include <hip/hip_runtime.h>
#include <math.h>

#define HIDN 512
#define PROJ 1024
#define ATTN 128
#define BATCH 4
#define SEQ 2048
#define N1 (2*PROJ+ATTN)      // 2176
#define ROWS (BATCH*SEQ)      // 8192
#define QR 16                 // q-rows per qksm block

typedef __attribute__((ext_vector_type(4))) float f32x4;
typedef __attribute__((ext_vector_type(8))) short bf16x8;

// bf16 <-> f32 via bit ops (round-to-nearest-even), no header dependency
__device__ __forceinline__ short f2bf(float x){
    unsigned u = __builtin_bit_cast(unsigned, x);
    unsigned rounding = 0x7fffu + ((u >> 16) & 1u);
    u += rounding;
    return (short)(u >> 16);
}
__device__ __forceinline__ float bf2f(short s){
    unsigned u = ((unsigned)(unsigned short)s) << 16;
    return __builtin_bit_cast(float, u);
}

__device__ __forceinline__ void gload16(const void* g, void* l){
    __builtin_amdgcn_global_load_lds((const __attribute__((address_space(1))) void*)g,
                                     (__attribute__((address_space(3))) void*)l,
                                     16, 0, 0);
}

// ---------------- double-buffered bt-GEMM tile: C[128x128] = A[M][K] @ BT[N][K]^T
// 256 threads (4 waves, 2x2), 16x16x32 bf16 MFMA.
// T3 minimum-2-phase: stage(next) issued BEFORE compute(cur); ONE barrier/K-step
// (compiler emits vmcnt(0)+lgkmcnt(0) before s_barrier -> prefetch drains after MFMA).
// T2 swizzle: LDS holds col-slot s at source slot s^(row&7) (pre-swizzled global src,
// linear gload_lds dest); ds_read applies the same XOR -> 8 lanes/16B-slot (LDS BW floor).
template<class Epi>
__device__ __forceinline__ void gemm_bt_tile(const short* __restrict__ A, int lda,
                                             const short* __restrict__ BT, int ldb,
                                             int m0, int n0, int K, Epi epi)
{
    __shared__ __align__(16) short lA[2][128*64];
    __shared__ __align__(16) short lB[2][128*64];
    const int t = threadIdx.x;
    const int lane = t & 63;
    const int w = t >> 6;
    const int wr = (w >> 1) * 64, wc = (w & 1) * 64;
    const int half = lane >> 4, l16 = lane & 15;

    f32x4 acc[4][4];
    #pragma unroll
    for (int i=0;i<4;i++)
        #pragma unroll
        for (int j=0;j<4;j++)
            acc[i][j] = (f32x4){0.f,0.f,0.f,0.f};

    auto stage = [&](int buf, int k0){
        #pragma unroll
        for (int i = 0; i < 4; i++) {
            int li = i*256 + t;
            int r = li >> 3, s = li & 7;
            int ss = s ^ (r & 7);                 // inverse-swizzled source slot
            gload16(A + (size_t)(m0+r)*lda + k0 + ss*8, lA[buf] + li*8);
        }
        #pragma unroll
        for (int i = 0; i < 4; i++) {
            int li = i*256 + t;
            int r = li >> 3, s = li & 7;
            int ss = s ^ (r & 7);
            gload16(BT + (size_t)(n0+r)*ldb + k0 + ss*8, lB[buf] + li*8);
        }
    };

    stage(0, 0);
    __syncthreads();
    int cur = 0;
    for (int k0 = 64; k0 <= K; k0 += 64) {
        if (k0 < K) stage(cur^1, k0);             // prefetch next tile (in flight during MFMA)
        #pragma unroll
        for (int kk = 0; kk < 64; kk += 32) {
            bf16x8 af[4], bfr[4];
            const int cs = (kk >> 3) + half;      // col slot 0..7
            #pragma unroll
            for (int i=0;i<4;i++){
                int row = wr + i*16 + l16;
                af[i] = *(const bf16x8*)(lA[cur] + row*64 + ((cs ^ (row & 7)) << 3));
            }
            #pragma unroll
            for (int j=0;j<4;j++){
                int row = wc + j*16 + l16;
                bfr[j] = *(const bf16x8*)(lB[cur] + row*64 + ((cs ^ (row & 7)) << 3));
            }
            #pragma unroll
            for (int i=0;i<4;i++)
                #pragma unroll
                for (int j=0;j<4;j++)
                    acc[i][j] = __builtin_amdgcn_mfma_f32_16x16x32_bf16(af[i], bfr[j], acc[i][j], 0, 0, 0);
        }
        __syncthreads();                          // drains prefetch (vmcnt0) + read-done fence
        cur ^= 1;
    }
    // C/D layout: col = lane&15, row = (lane>>4)*4 + q   [m89/m91 verified]
    #pragma unroll
    for (int i=0;i<4;i++)
        #pragma unroll
        for (int j=0;j<4;j++)
            #pragma unroll
            for (int q=0;q<4;q++)
                epi(m0 + wr + i*16 + half*4 + q, n0 + wc + j*16 + l16, acc[i][j][q]);
}

// ---------------- helpers ----------------
__global__ void k_cast_node(const float* __restrict__ in, short* __restrict__ out){
    int idx = blockIdx.x*256 + threadIdx.x;
    const float4 v = ((const float4*)in)[idx];
    short4 o; o.x = f2bf(v.x); o.y = f2bf(v.y); o.z = f2bf(v.z); o.w = f2bf(v.w);
    ((short4*)out)[idx] = o;
}

__global__ void k_transpose_cast(const float* __restrict__ in, short* __restrict__ out,
                                 int R, int C){
    __shared__ short tile[64][65];
    int r0 = blockIdx.y*64, c0 = blockIdx.x*64;
    int t = threadIdx.x;
    #pragma unroll
    for (int i=0;i<16;i++){
        int lin = i*256 + t; int r = lin>>6, c = lin&63;
        tile[r][c] = f2bf(in[(size_t)(r0+r)*C + c0+c]);
    }
    __syncthreads();
    #pragma unroll
    for (int i=0;i<16;i++){
        int lin = i*256 + t; int c = lin>>6, r = lin&63;
        out[(size_t)(c0+c)*R + r0+r] = tile[r][c];
    }
}

__global__ void k_transpose_v(const short* __restrict__ values, short* __restrict__ VT){
    __shared__ short tile[64][65];
    int z = blockIdx.z;
    int c0 = blockIdx.x*64, r0 = blockIdx.y*64;
    int t = threadIdx.x;
    #pragma unroll
    for (int i=0;i<16;i++){
        int lin = i*256 + t; int r = lin>>6, c = lin&63;
        tile[r][c] = values[(size_t)(z*SEQ + r0+r)*PROJ + c0+c];
    }
    __syncthreads();
    #pragma unroll
    for (int i=0;i<16;i++){
        int lin = i*256 + t; int c = lin>>6, r = lin&63;
        VT[((size_t)z*PROJ + c0+c)*SEQ + r0+r] = tile[r][c];
    }
}

// ---------------- GEMM1: silu(node@w1+b1) -> gates/values/base (bf16)
// 1D grid, XCD-chunked swizzle (1088 blocks = 8*136)
__global__ __launch_bounds__(256) void k_mm1(const short* __restrict__ nodeb,
        const short* __restrict__ w1T, const float* __restrict__ b1,
        short* __restrict__ gates, short* __restrict__ values, short* __restrict__ baseb){
    int b = blockIdx.x;
    int wg = (b & 7) * (N1/128*64/8) + (b >> 3);   // cpx = 136
    int n0 = (wg % (N1/128))*128, m0 = (wg / (N1/128))*128;
    gemm_bt_tile(nodeb, HIDN, w1T, HIDN, m0, n0, HIDN,
        [=](int row, int col, float v){
            v += b1[col];
            v = v / (1.f + __expf(-v));
            short bv = f2bf(v);
            if (col < PROJ)        gates [(size_t)row*PROJ + col]        = bv;
            else if (col < 2*PROJ) values[(size_t)row*PROJ + col-PROJ]   = bv;
            else                   baseb [(size_t)row*ATTN + col-2*PROJ] = bv;
        });
}

// ---------------- RoPE
__global__ void k_rope2(const short* __restrict__ baseb, const float* __restrict__ msw,
                        const float* __restrict__ msb, const float* __restrict__ scaling,
                        short* __restrict__ qb, short* __restrict__ kb){
    int idx = blockIdx.x*256 + threadIdx.x;
    int d = idx & 63;
    int row = idx >> 6;
    int l = row & (SEQ-1);
    float inv = exp2f(-(float)d * (13.287712379549449f/64.f));
    float ang = (float)l * inv;
    float s = sinf(ang), c = cosf(ang);
    const short* bp = baseb + (size_t)row*ATTN;
    float b_lo = bf2f(bp[d]), b_hi = bf2f(bp[d+64]);
    float x1q = b_lo*msw[d]        + msb[d];
    float x2q = b_hi*msw[d+64]     + msb[d+64];
    float x1k = b_lo*msw[128+d]    + msb[128+d];
    float x2k = b_hi*msw[128+d+64] + msb[128+d+64];
    float sc = scaling[0];
    qb[(size_t)row*ATTN + d]    = f2bf((x1q*c - x2q*s)*sc);
    qb[(size_t)row*ATTN + d+64] = f2bf((x2q*c + x1q*s)*sc);
    kb[(size_t)row*ATTN + d]    = f2bf(x1k*c - x2k*s);
    kb[(size_t)row*ATTN + d+64] = f2bf(x2k*c + x1k*s);
}

// ---------------- QK^T + bias + softmax -> compact bf16 P, ONE traversal.
// 512 threads / 8 waves; wave w owns 256 kv; S = 16 f32x4/lane (64 VGPR).
// Bias chunks (16x256 f32) register-prefetched one ahead. S^T = K.Q^T layout.
__global__ __launch_bounds__(512, 4) void k_qksm(
        const short* __restrict__ qg, const short* __restrict__ kg,
        const float* __restrict__ bias, short* __restrict__ P)
{
    __shared__ float bt[16][260];        // bias chunk, pad 4
    __shared__ short pt[16][264];        // P chunk bounce
    __shared__ float s_m[8][16];
    __shared__ float s_l[8][16];

    const int z = blockIdx.y;
    const int r0 = blockIdx.x * QR;
    const int t = threadIdx.x;
    const int w = t >> 6;                // 0..7
    const int lane = t & 63;
    const int l16 = lane & 15, half = lane >> 4;

    const short* Q  = qg + ((size_t)z*SEQ + r0)*ATTN;
    const short* K  = kg + (size_t)z*SEQ*ATTN;
    const float* Bb = bias + ((size_t)z*SEQ + r0)*SEQ;
    short* Pp = P + ((size_t)z*SEQ + r0)*SEQ;

    // Q B-frags (rows q = l16)
    bf16x8 qf[4];
    #pragma unroll
    for (int kc=0;kc<4;kc++)
        qf[kc] = *(const bf16x8*)(Q + (size_t)l16*ATTN + kc*32 + half*8);

    f32x4 acc[16];
    #pragma unroll
    for (int qd=0; qd<16; qd++) acc[qd] = (f32x4){0.f,0.f,0.f,0.f};

    // bias prefetch: thread t stages units t (rows 0-7) and t+512 (rows 8-15)
    const int brow = t >> 6, bcol = (t & 63)*4;
    f32x4 pr0 = *(const f32x4*)(Bb + (size_t)brow*SEQ + bcol);
    f32x4 pr1 = *(const f32x4*)(Bb + (size_t)(8+brow)*SEQ + bcol);

    // ---- phase 1: S = K.Q^T + bias, accumulate in registers
    #pragma unroll
    for (int c=0; c<8; c++){
        __syncthreads();                  // prev chunk's bt reads complete
        *(f32x4*)&bt[brow][bcol]   = pr0;
        *(f32x4*)&bt[8+brow][bcol] = pr1;
        __syncthreads();                  // bt ready
        if (c < 7){
            pr0 = *(const f32x4*)(Bb + (size_t)brow*SEQ + (c+1)*256 + bcol);
            pr1 = *(const f32x4*)(Bb + (size_t)(8+brow)*SEQ + (c+1)*256 + bcol);
        }
        #pragma unroll
        for (int i=0;i<2;i++){
            int qd = c*2 + i;
            int tile = w*2 + i;           // 16-kv tile within chunk
            const short* Kc = K + (size_t)(c*256 + tile*16 + l16)*ATTN;
            #pragma unroll
            for (int kc=0;kc<4;kc++){
                bf16x8 kf = *(const bf16x8*)(Kc + kc*32 + half*8);
                acc[qd] = __builtin_amdgcn_mfma_f32_16x16x32_bf16(kf, qf[kc], acc[qd], 0,0,0);
            }
            acc[qd] += *(const f32x4*)&bt[l16][tile*16 + half*4];
        }
    }

    // ---- phase 2: stats for q = l16 (wave covers 256 kv; 8 waves total)
    float tm = -3e38f;
    #pragma unroll
    for (int qd=0; qd<16; qd++)
        tm = fmaxf(tm, fmaxf(fmaxf(acc[qd][0],acc[qd][1]), fmaxf(acc[qd][2],acc[qd][3])));
    tm = fmaxf(tm, __shfl_xor(tm,16,64));
    tm = fmaxf(tm, __shfl_xor(tm,32,64));
    if (half==0) s_m[w][l16] = tm;
    __syncthreads();
    float m = -3e38f;
    #pragma unroll
    for (int ww=0; ww<8; ww++) m = fmaxf(m, s_m[ww][l16]);
    float ts = 0.f;
    #pragma unroll
    for (int qd=0; qd<16; qd++){
        acc[qd][0] = __expf(acc[qd][0]-m);
        acc[qd][1] = __expf(acc[qd][1]-m);
        acc[qd][2] = __expf(acc[qd][2]-m);
        acc[qd][3] = __expf(acc[qd][3]-m);
        ts += acc[qd][0]+acc[qd][1]+acc[qd][2]+acc[qd][3];
    }
    ts += __shfl_xor(ts,16,64);
    ts += __shfl_xor(ts,32,64);
    if (half==0) s_l[w][l16] = ts;
    __syncthreads();
    float sum = 0.f;
    #pragma unroll
    for (int ww=0; ww<8; ww++) sum += s_l[ww][l16];
    const float inv = 1.f/sum;

    // ---- phase 3: normalize, pack bf16, coalesced store via LDS bounce
    #pragma unroll
    for (int c=0; c<8; c++){
        #pragma unroll
        for (int i=0;i<2;i++){
            int qd = c*2 + i;
            int kvloc = (w*2 + i)*16 + half*4;
            f32x4 p4 = acc[qd] * inv;
            unsigned u0 = (unsigned)(unsigned short)f2bf(p4[0]) | ((unsigned)(unsigned short)f2bf(p4[1])<<16);
            unsigned u1 = (unsigned)(unsigned short)f2bf(p4[2]) | ((unsigned)(unsigned short)f2bf(p4[3])<<16);
            *(unsigned*)&pt[l16][kvloc]     = u0;
            *(unsigned*)&pt[l16][kvloc + 2] = u1;
        }
        __syncthreads();
        {
            int row = t >> 5, colg = t & 31;   // 512 threads = 16 rows x 32 groups
            *(bf16x8*)(Pp + (size_t)row*SEQ + c*256 + colg*8) =
                *(const bf16x8*)&pt[row][colg*8];
        }
        __syncthreads();
    }
}

// ---------------- PV: a2 = (P @ V) * gates  (bf16 out)
// 1D grid, XCD-chunked swizzle (512 blocks = 8*64)
__global__ __launch_bounds__(256) void k_pv2(const short* __restrict__ P,
        const short* __restrict__ VT, const short* __restrict__ gates,
        short* __restrict__ a2){
    int b = blockIdx.x;
    int wg = (b & 7) * 64 + (b >> 3);
    int xx = wg & 7, yy = (wg >> 3) & 15, z = wg >> 7;
    const short* A = P  + (size_t)z*SEQ*SEQ;
    const short* B = VT + (size_t)z*PROJ*SEQ;
    int n0 = xx*128, m0 = yy*128;
    gemm_bt_tile(A, SEQ, B, SEQ, m0, n0, SEQ,
        [=](int r, int c, float v){
            size_t gi = ((size_t)z*SEQ + r)*PROJ + c;
            a2[gi] = f2bf(v * bf2f(gates[gi]));
        });
}

// ---------------- GEMM2: out = a2 @ w2 + b2  (f32 out)
// 1D grid, XCD-chunked swizzle (256 blocks = 8*32)
__global__ __launch_bounds__(256) void k_mm2(const short* __restrict__ a2,
        const short* __restrict__ w2T, const float* __restrict__ b2,
        float* __restrict__ out){
    int b = blockIdx.x;
    int wg = (b & 7) * 32 + (b >> 3);
    int n0 = (wg & 3)*128, m0 = (wg >> 2)*128;
    gemm_bt_tile(a2, PROJ, w2T, PROJ, m0, n0, PROJ,
        [=](int r, int c, float v){
            out[(size_t)r*HIDN + c] = v + b2[c];
        });
}

extern "C" void kernel_launch(void* const* d_in, const int* in_sizes, int n_in,
                              void* d_out, int out_size, void* d_ws, size_t ws_size,
                              hipStream_t stream) {
    const float* node    = (const float*)d_in[0];
    const float* bias    = (const float*)d_in[1];
    const float* scaling = (const float*)d_in[2];
    const float* w1      = (const float*)d_in[3];
    const float* b1      = (const float*)d_in[4];
    const float* msw     = (const float*)d_in[5];
    const float* msb     = (const float*)d_in[6];
    const float* w2      = (const float*)d_in[7];
    const float* b2      = (const float*)d_in[8];
    float* out = (float*)d_out;

    char* p = (char*)d_ws;
    auto alloc = [&](size_t bytes){ char* r = p; p += (bytes + 255) & ~(size_t)255; return r; };
    short* nodeb  = (short*)alloc((size_t)ROWS*HIDN*2);
    short* w1T    = (short*)alloc((size_t)N1*HIDN*2);
    short* w2T    = (short*)alloc((size_t)HIDN*PROJ*2);
    short* gates  = (short*)alloc((size_t)ROWS*PROJ*2);
    short* values = (short*)alloc((size_t)ROWS*PROJ*2);
    short* VT     = (short*)alloc((size_t)BATCH*PROJ*SEQ*2);
    short* baseb  = (short*)alloc((size_t)ROWS*ATTN*2);
    short* qb     = (short*)alloc((size_t)ROWS*ATTN*2);
    short* kb     = (short*)alloc((size_t)ROWS*ATTN*2);
    short* Pbuf   = (short*)alloc((size_t)BATCH*SEQ*SEQ*2);
    short* a2buf  = (short*)alloc((size_t)ROWS*PROJ*2);

    k_cast_node<<<ROWS*HIDN/1024, 256, 0, stream>>>(node, nodeb);
    k_transpose_cast<<<dim3(N1/64, HIDN/64), 256, 0, stream>>>(w1, w1T, HIDN, N1);
    k_transpose_cast<<<dim3(HIDN/64, PROJ/64), 256, 0, stream>>>(w2, w2T, PROJ, HIDN);
    // 1) gva = silu(node@w1+b1)
    k_mm1<<<(N1/128)*(ROWS/128), 256, 0, stream>>>(nodeb, w1T, b1, gates, values, baseb);
    // transpose values for PV B^T layout
    k_transpose_v<<<dim3(PROJ/64, SEQ/64, BATCH), 256, 0, stream>>>(values, VT);
    // 2) rope
    k_rope2<<<ROWS*64/256, 256, 0, stream>>>(baseb, msw, msb, scaling, qb, kb);
    // 3) one-traversal qk^T + bias + softmax -> P (bf16), 8 waves/block
    k_qksm<<<dim3(SEQ/QR, BATCH), 512, 0, stream>>>(qb, kb, bias, Pbuf);
    // 3c) a2 = (P@V)*gates
    k_pv2<<<(PROJ/128)*(SEQ/128)*BATCH, 256, 0, stream>>>(Pbuf, VT, gates, a2buf);
    // 4) out = a2@w2 + b2
    k_mm2<<<(HIDN/128)*(ROWS/128), 256, 0, stream>>>(a2buf, w2T, b2, out);
}